// Round 1
// 1095.003 us; speedup vs baseline: 1.0205x; 1.0205x over previous
//
#include <hip/hip_runtime.h>
#include <hip/hip_bf16.h>

#define B_SZ 1024
#define KNEG 5
#define VOC 32000
#define DIM 128
#define NSPLIT 50              // k1 K-splits
#define VSLICE 640             // VOC / NSPLIT
#define NS (VSLICE / 32)       // 20 MFMA K-steps per slice

typedef __bf16 bf16x8 __attribute__((ext_vector_type(8)));
typedef float f32x4 __attribute__((ext_vector_type(4)));

// ---- ws layout (bytes) ----
// Ub      @ 0         : VOC*DIM bf16   = 8,192,000
// Vt      @ 8192000   : DIM*VOC bf16   = 8,192,000
// partial @ 16384000  : 50*B*DIM f32   = 26,214,400
// vie     @ 42598400  : B*DIM bf16     = 262,144
// pos_dot @ 42860544  : B f32          = 4,096
// neg_dot @ 42864640  : B*KNEG f32     = 20,480

__device__ __forceinline__ float logsig(float x) {
    return fminf(x, 0.0f) - log1pf(expf(-fabsf(x)));
}

// K0: Ub[v][d] = bf16(U[v][d]);  Vt[d][v] = bf16(V[v][d])  (32x32 LDS transpose)
__global__ __launch_bounds__(256) void k0_convert(
    const float* __restrict__ V, const float* __restrict__ U,
    __bf16* __restrict__ Vt, __bf16* __restrict__ Ub) {
    __shared__ float tile[32][33];
    int bid = blockIdx.x;
    int vt = bid >> 2;
    int dt = bid & 3;
    int v0 = vt * 32, d0 = dt * 32;
    int t = threadIdx.x;
    int lr = t >> 5;
    int lc = t & 31;
#pragma unroll
    for (int i = 0; i < 4; ++i) {
        int r = lr + i * 8;
        size_t idx = (size_t)(v0 + r) * DIM + d0 + lc;
        tile[r][lc] = V[idx];
        Ub[idx] = (__bf16)U[idx];
    }
    __syncthreads();
#pragma unroll
    for (int i = 0; i < 4; ++i) {
        int r = lr + i * 8;
        Vt[(size_t)(d0 + r) * VOC + v0 + lc] = (__bf16)tile[lc][r];
    }
}

// K1 (wave-autonomous): each wave owns a 16-row b-tile over a 640-v K-slice.
// No LDS, no cross-wave reduction. grid (16 m64-tiles, 50 splits).
__global__ __launch_bounds__(256) void k1_viembed(
    const float* __restrict__ vi, const __bf16* __restrict__ Vt,
    float* __restrict__ partial) {
    int mt = blockIdx.x;           // 0..15 : 64 b-rows per block
    int sp = blockIdx.y;           // 0..49 : 640-v slice
    int wave = threadIdx.x >> 6;
    int lane = threadIdx.x & 63;
    int n16 = lane & 15;
    int q = lane >> 4;
    int brow = mt * 64 + wave * 16;   // this wave's 16-row tile

    f32x4 acc[8];
#pragma unroll
    for (int ct = 0; ct < 8; ++ct) acc[ct] = (f32x4){0.f, 0.f, 0.f, 0.f};

    int v_base = sp * VSLICE;
    const float* arow = vi + (size_t)(brow + n16) * VOC + v_base + q * 8;
#pragma unroll 2
    for (int s = 0; s < NS; ++s) {
        int kk = v_base + s * 32 + q * 8;
        float4 x0 = *(const float4*)(arow + s * 32);
        float4 x1 = *(const float4*)(arow + s * 32 + 4);
        bf16x8 a;
        a[0] = (__bf16)x0.x; a[1] = (__bf16)x0.y;
        a[2] = (__bf16)x0.z; a[3] = (__bf16)x0.w;
        a[4] = (__bf16)x1.x; a[5] = (__bf16)x1.y;
        a[6] = (__bf16)x1.z; a[7] = (__bf16)x1.w;
#pragma unroll
        for (int ct = 0; ct < 8; ++ct) {
            // all 4 waves read identical bfrags -> L1 dedup within the CU
            bf16x8 bfrag = *(const bf16x8*)(Vt + (size_t)(ct * 16 + n16) * VOC + kk);
            acc[ct] = __builtin_amdgcn_mfma_f32_16x16x32_bf16(a, bfrag, acc[ct], 0, 0, 0);
        }
    }
    // C layout (16x16x32): row = q*4+r, col = n16
    float* pb = partial + ((size_t)sp * B_SZ + brow) * DIM;
#pragma unroll
    for (int ct = 0; ct < 8; ++ct)
#pragma unroll
        for (int r = 0; r < 4; ++r)
            pb[(size_t)(q * 4 + r) * DIM + ct * 16 + n16] = acc[ct][r];
}

// K2: sum 50 split partials -> vi_embed bf16
__global__ __launch_bounds__(256) void k2_reduce(
    const float* __restrict__ partial, __bf16* __restrict__ vie) {
    int idx = blockIdx.x * 256 + threadIdx.x;
    float s = 0.f;
#pragma unroll
    for (int sp = 0; sp < NSPLIT; ++sp) s += partial[(size_t)sp * (B_SZ * DIM) + idx];
    vie[idx] = (__bf16)s;
}

// K3: one 256-v chunk per block. phase A computes W[32b][256v] via MFMA into
// LDS; phase B streams vo/neg with float4 loads against LDS W.
// grid (32 bt, 125 vc) = 4000 blocks -> 5 blocks/CU resident (32 KB LDS).
__global__ __launch_bounds__(256) void k3_fused(
    const __bf16* __restrict__ vie, const float* __restrict__ vo,
    const float* __restrict__ neg, const __bf16* __restrict__ Ub,
    float* __restrict__ pos_dot, float* __restrict__ neg_dot) {
    __shared__ float W[32 * 256];   // 32 KB
    int bt = blockIdx.x;
    int vc = blockIdx.y;
    int t = threadIdx.x;
    int wave = t >> 6, lane = t & 63, n16 = lane & 15, q = lane >> 4;
    int b0 = bt * 32;
    int vbase = vc * 256;

    // A-frags (vie rows) register-resident
    bf16x8 afrag[2][4];
#pragma unroll
    for (int rt = 0; rt < 2; ++rt) {
        int b = b0 + rt * 16 + n16;
#pragma unroll
        for (int ks = 0; ks < 4; ++ks)
            afrag[rt][ks] = *(const bf16x8*)(vie + (size_t)b * DIM + ks * 32 + q * 8);
    }

    // ---- phase A: 16 v-tiles of 16; wave handles tiles wave*4 .. wave*4+3
#pragma unroll
    for (int j = 0; j < 4; ++j) {
        int tt = wave * 4 + j;
        int v0 = vbase + tt * 16;
        f32x4 w0 = (f32x4){0.f, 0.f, 0.f, 0.f};
        f32x4 w1 = (f32x4){0.f, 0.f, 0.f, 0.f};
#pragma unroll
        for (int ks = 0; ks < 4; ++ks) {
            bf16x8 bfrag = *(const bf16x8*)(Ub + (size_t)(v0 + n16) * DIM + ks * 32 + q * 8);
            w0 = __builtin_amdgcn_mfma_f32_16x16x32_bf16(afrag[0][ks], bfrag, w0, 0, 0, 0);
            w1 = __builtin_amdgcn_mfma_f32_16x16x32_bf16(afrag[1][ks], bfrag, w1, 0, 0, 0);
        }
        int col = tt * 16 + n16;
#pragma unroll
        for (int r = 0; r < 4; ++r) {
            W[(q * 4 + r) * 256 + col] = w0[r];        // rows 0..15  (rt=0)
            W[(16 + q * 4 + r) * 256 + col] = w1[r];   // rows 16..31 (rt=1)
        }
    }
    __syncthreads();

    // ---- phase B: vectorized stream of vo/neg against LDS W
    int rowB = t >> 3;   // 0..31: which b-row this thread streams
    int lcol = t & 7;    // 8 threads per row, float4 each -> 32 v per i-step
    float acc[6] = {0.f, 0.f, 0.f, 0.f, 0.f, 0.f};

    const float* vop = vo + (size_t)(b0 + rowB) * VOC + vbase + lcol * 4;
    const float* negp[KNEG];
#pragma unroll
    for (int k = 0; k < KNEG; ++k)
        negp[k] = neg + ((size_t)(b0 + rowB) * KNEG + k) * VOC + vbase + lcol * 4;

#pragma unroll
    for (int i = 0; i < 8; ++i) {
        float4 wv = *(const float4*)&W[rowB * 256 + lcol * 4 + i * 32];
        float4 x = *(const float4*)(vop + i * 32);
        acc[0] += x.x * wv.x + x.y * wv.y + x.z * wv.z + x.w * wv.w;
#pragma unroll
        for (int k = 0; k < KNEG; ++k) {
            float4 y = *(const float4*)(negp[k] + i * 32);
            acc[1 + k] += y.x * wv.x + y.y * wv.y + y.z * wv.z + y.w * wv.w;
        }
    }

    // reduce the 8 threads sharing rowB (consecutive lanes), one atomic each
#pragma unroll
    for (int j = 0; j < 6; ++j) {
        float s = acc[j];
        s += __shfl_xor(s, 1, 8);
        s += __shfl_xor(s, 2, 8);
        s += __shfl_xor(s, 4, 8);
        if (lcol == 0) {
            int b = b0 + rowB;
            if (j == 0) atomicAdd(&pos_dot[b], s);
            else atomicAdd(&neg_dot[b * KNEG + (j - 1)], s);
        }
    }
}

// K4: loss = mean_b -( logsig(pos[b]) + sum_k logsig(-neg[b][k]) )
__global__ __launch_bounds__(256) void k4_final(
    const float* __restrict__ pos_dot, const float* __restrict__ neg_dot,
    float* __restrict__ out) {
    __shared__ float wsum[4];
    int t = threadIdx.x;
    float s = 0.f;
    for (int b = t; b < B_SZ; b += 256) {
        float left = logsig(pos_dot[b]);
        float right = 0.f;
#pragma unroll
        for (int k = 0; k < KNEG; ++k) right += logsig(-neg_dot[b * KNEG + k]);
        s += -(left + right);
    }
#pragma unroll
    for (int m = 32; m >= 1; m >>= 1) s += __shfl_xor(s, m, 64);
    if ((t & 63) == 0) wsum[t >> 6] = s;
    __syncthreads();
    if (t == 0) out[0] = (wsum[0] + wsum[1] + wsum[2] + wsum[3]) * (1.0f / B_SZ);
}

extern "C" void kernel_launch(void* const* d_in, const int* in_sizes, int n_in,
                              void* d_out, int out_size, void* d_ws, size_t ws_size,
                              hipStream_t stream) {
    const float* vi  = (const float*)d_in[0];
    const float* vo  = (const float*)d_in[1];
    const float* neg = (const float*)d_in[2];
    const float* V   = (const float*)d_in[3];
    const float* U   = (const float*)d_in[4];

    char* ws = (char*)d_ws;
    __bf16* Ub      = (__bf16*)(ws);
    __bf16* Vt      = (__bf16*)(ws + 8192000);
    float*  partial = (float*) (ws + 16384000);
    __bf16* vie     = (__bf16*)(ws + 42598400);
    float*  pos_dot = (float*) (ws + 42860544);
    float*  neg_dot = (float*) (ws + 42864640);
    float*  out     = (float*)d_out;

    hipMemsetAsync(ws + 42860544, 0, 4096 + 20480, stream);  // pos_dot + neg_dot

    k0_convert<<<4000, 256, 0, stream>>>(V, U, Vt, Ub);
    k1_viembed<<<dim3(16, 50), 256, 0, stream>>>(vi, Vt, partial);
    k2_reduce<<<512, 256, 0, stream>>>(partial, vie);
    k3_fused<<<dim3(32, 125), 256, 0, stream>>>(vie, vo, neg, Ub, pos_dot, neg_dot);
    k4_final<<<1, 256, 0, stream>>>(pos_dot, neg_dot, out);
}